// Round 1
// baseline (510.414 us; speedup 1.0000x reference)
//
#include <hip/hip_runtime.h>

#define B 32
#define C 512
#define HW 4096            // 64*64
#define K 256              // int(0.5 * C)

__inline__ __device__ float wave_reduce(float v) {
    #pragma unroll
    for (int o = 32; o > 0; o >>= 1) v += __shfl_down(v, o, 64);
    return v;
}

// Kernel 1: one block per (b,c) plane. Computes sum(tgt^2) and sum((in-tgt)^2)
// over the 4096 spatial elements. Pure HBM stream: 32 KB read per block.
__global__ __launch_bounds__(256) void plane_reduce(
        const float* __restrict__ in, const float* __restrict__ tgt,
        float* __restrict__ norm2, float* __restrict__ ssd) {
    const int plane = blockIdx.x;                 // b*C + c
    const size_t base = (size_t)plane * HW;
    const float4* __restrict__ in4 = (const float4*)(in  + base);
    const float4* __restrict__ tg4 = (const float4*)(tgt + base);

    float t2 = 0.f, d2 = 0.f;
    #pragma unroll
    for (int i = 0; i < 4; ++i) {                 // 1024 float4 / 256 threads = 4
        const int j = threadIdx.x + i * 256;
        const float4 a = in4[j];
        const float4 t = tg4[j];
        const float dx = a.x - t.x, dy = a.y - t.y, dz = a.z - t.z, dw = a.w - t.w;
        t2 += t.x * t.x + t.y * t.y + t.z * t.z + t.w * t.w;
        d2 += dx * dx + dy * dy + dz * dz + dw * dw;
    }

    t2 = wave_reduce(t2);
    d2 = wave_reduce(d2);

    __shared__ float st[4], sd[4];
    const int lane = threadIdx.x & 63, wid = threadIdx.x >> 6;
    if (lane == 0) { st[wid] = t2; sd[wid] = d2; }
    __syncthreads();
    if (threadIdx.x == 0) {
        norm2[plane] = st[0] + st[1] + st[2] + st[3];
        ssd[plane]   = sd[0] + sd[1] + sd[2] + sd[3];
    }
}

// Kernel 2: one block per batch element. Exact top-k by rank with jax
// tie-breaking (equal norms -> lower index wins). Masked sum of ssd.
__global__ __launch_bounds__(C) void topk_mask_sum(
        const float* __restrict__ norm2, const float* __restrict__ ssd,
        float* __restrict__ bsum) {
    __shared__ float sn[C];
    __shared__ float red[C / 64];
    const int b = blockIdx.x, c = threadIdx.x;
    sn[c] = norm2[b * C + c];
    __syncthreads();

    const float my = sn[c];
    int rank = 0;
    #pragma unroll 8
    for (int j = 0; j < C; ++j) {
        const float o = sn[j];
        rank += (o > my) || (o == my && j < c);
    }
    float v = (rank < K) ? ssd[b * C + c] : 0.f;

    v = wave_reduce(v);
    const int lane = c & 63, wid = c >> 6;
    if (lane == 0) red[wid] = v;
    __syncthreads();
    if (c < 64) {
        float r = (c < C / 64) ? red[c] : 0.f;
        r = wave_reduce(r);
        if (c == 0) bsum[b] = r;
    }
}

// Kernel 3: fold 32 per-batch partials, apply /HW (spatial mean) and
// /sum(mask)=B*K.
__global__ __launch_bounds__(64) void finalize(
        const float* __restrict__ bsum, float* __restrict__ out) {
    float v = (threadIdx.x < B) ? bsum[threadIdx.x] : 0.f;
    v = wave_reduce(v);
    if (threadIdx.x == 0)
        out[0] = v / ((float)HW * (float)(B * K));
}

extern "C" void kernel_launch(void* const* d_in, const int* in_sizes, int n_in,
                              void* d_out, int out_size, void* d_ws, size_t ws_size,
                              hipStream_t stream) {
    const float* in  = (const float*)d_in[0];
    const float* tgt = (const float*)d_in[1];
    float* out = (float*)d_out;

    float* norm2 = (float*)d_ws;            // B*C floats
    float* ssd   = norm2 + B * C;           // B*C floats
    float* bsum  = ssd + B * C;             // B floats

    plane_reduce<<<B * C, 256, 0, stream>>>(in, tgt, norm2, ssd);
    topk_mask_sum<<<B, C, 0, stream>>>(norm2, ssd, bsum);
    finalize<<<1, 64, 0, stream>>>(bsum, out);
}